// Round 1
// baseline (253.418 us; speedup 1.0000x reference)
//
#include <hip/hip_runtime.h>
#include <hip/hip_bf16.h>
#include <cstdint>

typedef __attribute__((ext_vector_type(8))) short short8v;
typedef __attribute__((ext_vector_type(4))) float f32x4;

#define B_  8
#define H_  8
#define NQ_ 1024
#define NK_ 1024
#define DM_ 512
#define DK_ 64

__device__ __forceinline__ unsigned short f2bf(float f) {
  unsigned u = __float_as_uint(f);
  u += 0x7FFF + ((u >> 16) & 1);
  return (unsigned short)(u >> 16);
}

// ---------------- f32 -> bf16 bulk convert (8 elems/thread) ----------------
__global__ __launch_bounds__(256) void conv_bf16(const float* __restrict__ src,
                                                 unsigned short* __restrict__ dst,
                                                 int n8) {
  int i = blockIdx.x * 256 + threadIdx.x;
  if (i >= n8) return;
  const float4* s4 = (const float4*)src + (size_t)i * 2;
  float4 a = s4[0], b = s4[1];
  short8v o;
  o[0] = (short)f2bf(a.x); o[1] = (short)f2bf(a.y);
  o[2] = (short)f2bf(a.z); o[3] = (short)f2bf(a.w);
  o[4] = (short)f2bf(b.x); o[5] = (short)f2bf(b.y);
  o[6] = (short)f2bf(b.z); o[7] = (short)f2bf(b.w);
  *(short8v*)(dst + (size_t)i * 8) = o;
}

// ---------------- W [512][512] f32 -> Wt [512][512] bf16 (Wt[n][k]=W[k][n]) ----------------
__global__ __launch_bounds__(256) void transpose_w(const float* __restrict__ src,
                                                   unsigned short* __restrict__ dst) {
  int i = blockIdx.x * 256 + threadIdx.x;  // 512*512 total
  int k = i >> 9, n = i & 511;
  dst[(size_t)n * 512 + k] = f2bf(src[i]);
}

// ---------------- bf16 GEMM: C[m][n] = sum_k A[m][k]*Bt[n][k] + bias[n] ----------------
// M=8192, N=512, K=512. BM=BN=128, BK=32, 4 waves (2x2), each wave 64x64.
// mode 0: q layout [B,H,N,64] bf16 ; 1: k layout ; 2: vT layout [B,H,64,N] bf16 ; 3: f32 to d_out
__global__ __launch_bounds__(256) void gemm_bf16(
    const unsigned short* __restrict__ A,
    const unsigned short* __restrict__ Bt,
    const float* __restrict__ bias,
    void* __restrict__ outp, int mode) {
  const int K = 512;
  const int LDA = 40;  // 32 + 8 pad -> 2-way bank conflicts only
  __shared__ unsigned short As[128 * 40];
  __shared__ unsigned short Bs[128 * 40];
  int t = threadIdx.x;
  int wave = t >> 6, lane = t & 63;
  int wr = wave >> 1, wc = wave & 1;
  int row0 = blockIdx.x * 128;
  int col0 = blockIdx.y * 128;
  f32x4 acc[4][4] = {};
  int sr = t >> 2, sc = (t & 3) * 8;
  const unsigned short* pa0 = A + (size_t)(row0 + sr) * K + sc;
  const unsigned short* pa1 = A + (size_t)(row0 + 64 + sr) * K + sc;
  const unsigned short* pb0 = Bt + (size_t)(col0 + sr) * K + sc;
  const unsigned short* pb1 = Bt + (size_t)(col0 + 64 + sr) * K + sc;
  int l15 = lane & 15, lk = (lane >> 4) * 8;
  for (int kb = 0; kb < K; kb += 32) {
    short8v va0 = *(const short8v*)(pa0 + kb);
    short8v va1 = *(const short8v*)(pa1 + kb);
    short8v vb0 = *(const short8v*)(pb0 + kb);
    short8v vb1 = *(const short8v*)(pb1 + kb);
    __syncthreads();
    *(short8v*)(As + sr * LDA + sc) = va0;
    *(short8v*)(As + (64 + sr) * LDA + sc) = va1;
    *(short8v*)(Bs + sr * LDA + sc) = vb0;
    *(short8v*)(Bs + (64 + sr) * LDA + sc) = vb1;
    __syncthreads();
    short8v af[4], bf[4];
#pragma unroll
    for (int i = 0; i < 4; ++i)
      af[i] = *(const short8v*)(As + (wr * 64 + i * 16 + l15) * LDA + lk);
#pragma unroll
    for (int j = 0; j < 4; ++j)
      bf[j] = *(const short8v*)(Bs + (wc * 64 + j * 16 + l15) * LDA + lk);
#pragma unroll
    for (int i = 0; i < 4; ++i)
#pragma unroll
      for (int j = 0; j < 4; ++j)
        acc[i][j] = __builtin_amdgcn_mfma_f32_16x16x32_bf16(af[i], bf[j], acc[i][j], 0, 0, 0);
  }
  int lr = (lane >> 4) * 4;
#pragma unroll
  for (int i = 0; i < 4; ++i) {
#pragma unroll
    for (int j = 0; j < 4; ++j) {
      int col = col0 + wc * 64 + j * 16 + l15;
      float bb = bias[col];
#pragma unroll
      for (int r = 0; r < 4; ++r) {
        int m = row0 + wr * 64 + i * 16 + lr + r;
        float v = acc[i][j][r] + bb;
        if (mode == 3) {
          ((float*)outp)[(size_t)m * 512 + col] = v;
        } else {
          int b = m >> 10, n = m & 1023, h = col >> 6, d = col & 63;
          unsigned short bw = f2bf(v);
          if (mode == 2)
            ((unsigned short*)outp)[(((size_t)b * H_ + h) * DK_ + d) * NK_ + n] = bw;
          else
            ((unsigned short*)outp)[(((size_t)b * H_ + h) * NQ_ + n) * DK_ + d] = bw;
        }
      }
    }
  }
}

// ---------------- fused attention ----------------
// grid: B*H*(NQ/64) = 1024 blocks, 256 threads (4 waves; wave w owns q-rows [16w,16w+16) of the 64-row block)
__global__ __launch_bounds__(256) void attn_fused(
    const unsigned short* __restrict__ qw,   // [B,H,NQ,64] bf16
    const unsigned short* __restrict__ kw,   // [B,H,NK,64] bf16
    const unsigned short* __restrict__ vtw,  // [B,H,64,NK] bf16 (V transposed)
    const int* __restrict__ mask,            // [B,NQ,NK] int32
    float* __restrict__ unnorm,              // [B,H,NQ,NK] f32 (output 1)
    unsigned short* __restrict__ ctx) {      // [B,NQ,512] bf16
  __shared__ unsigned short Qs[64 * 72];
  __shared__ unsigned short Ks[64 * 72];
  __shared__ unsigned short Vs[64 * 72];
  __shared__ unsigned short Ps[64 * 72];
  int bid = blockIdx.x;
  int qb = bid & 15, h = (bid >> 4) & 7, b = bid >> 7;
  int t = threadIdx.x, wave = t >> 6, lane = t & 63;
  int l15 = lane & 15, lg = lane >> 4;
  const unsigned short* qp = qw + (((size_t)b * H_ + h) * NQ_ + qb * 64) * 64;
  const unsigned short* kp = kw + ((size_t)b * H_ + h) * NK_ * 64;
  const unsigned short* vp = vtw + ((size_t)b * H_ + h) * 64 * NK_;
  for (int i = t; i < 512; i += 256) {
    int r = i >> 3, c = (i & 7) * 8;
    *(short8v*)(Qs + r * 72 + c) = *(const short8v*)(qp + (size_t)r * 64 + c);
  }
  __syncthreads();
  short8v aq0 = *(const short8v*)(Qs + (wave * 16 + l15) * 72 + lg * 8);
  short8v aq1 = *(const short8v*)(Qs + (wave * 16 + l15) * 72 + 32 + lg * 8);
  float mrow[4] = {-INFINITY, -INFINITY, -INFINITY, -INFINITY};
  float lsum[4] = {0.f, 0.f, 0.f, 0.f};
  f32x4 oacc[4] = {};
  int qrow0 = qb * 64 + wave * 16 + lg * 4;  // + r
  float* up_base = unnorm + ((size_t)(b * H_ + h) * NQ_ + qrow0) * NK_ + l15;
  const int* mp_base = mask + ((size_t)b * NQ_ + qrow0) * NK_ + l15;
  for (int kb = 0; kb < 16; ++kb) {
    __syncthreads();
    for (int i = t; i < 512; i += 256) {
      int r = i >> 3, c = (i & 7) * 8;
      *(short8v*)(Ks + r * 72 + c) = *(const short8v*)(kp + (size_t)(kb * 64 + r) * 64 + c);
      *(short8v*)(Vs + r * 72 + c) = *(const short8v*)(vp + (size_t)r * NK_ + kb * 64 + c);
    }
    __syncthreads();
    f32x4 s[4] = {};
#pragma unroll
    for (int j = 0; j < 4; ++j) {
      short8v bk0 = *(const short8v*)(Ks + (j * 16 + l15) * 72 + lg * 8);
      short8v bk1 = *(const short8v*)(Ks + (j * 16 + l15) * 72 + 32 + lg * 8);
      s[j] = __builtin_amdgcn_mfma_f32_16x16x32_bf16(aq0, bk0, s[j], 0, 0, 0);
      s[j] = __builtin_amdgcn_mfma_f32_16x16x32_bf16(aq1, bk1, s[j], 0, 0, 0);
    }
    float sv[4][4];
    float* up = up_base + kb * 64;
    const int* mp = mp_base + kb * 64;
#pragma unroll
    for (int j = 0; j < 4; ++j)
#pragma unroll
      for (int r = 0; r < 4; ++r) {
        float v = s[j][r] * 0.125f;
        up[(size_t)r * NK_ + j * 16] = v;                       // unmasked score output
        sv[j][r] = mp[(size_t)r * NK_ + j * 16] ? v : -INFINITY;
      }
    float alpha[4];
#pragma unroll
    for (int r = 0; r < 4; ++r) {
      float tm = fmaxf(fmaxf(sv[0][r], sv[1][r]), fmaxf(sv[2][r], sv[3][r]));
      tm = fmaxf(tm, __shfl_xor(tm, 1));
      tm = fmaxf(tm, __shfl_xor(tm, 2));
      tm = fmaxf(tm, __shfl_xor(tm, 4));
      tm = fmaxf(tm, __shfl_xor(tm, 8));
      float mnew = fmaxf(mrow[r], tm);
      alpha[r] = (mnew == -INFINITY) ? 1.0f : __expf(mrow[r] - mnew);
      mrow[r] = mnew;
    }
    float psum[4] = {0.f, 0.f, 0.f, 0.f};
#pragma unroll
    for (int j = 0; j < 4; ++j)
#pragma unroll
      for (int r = 0; r < 4; ++r) {
        float p = (sv[j][r] == -INFINITY) ? 0.0f : __expf(sv[j][r] - mrow[r]);
        psum[r] += p;
        Ps[(wave * 16 + lg * 4 + r) * 72 + j * 16 + l15] = f2bf(p);
      }
#pragma unroll
    for (int r = 0; r < 4; ++r) {
      float v = psum[r];
      v += __shfl_xor(v, 1); v += __shfl_xor(v, 2);
      v += __shfl_xor(v, 4); v += __shfl_xor(v, 8);
      lsum[r] = lsum[r] * alpha[r] + v;
#pragma unroll
      for (int j = 0; j < 4; ++j) oacc[j][r] *= alpha[r];
    }
#pragma unroll
    for (int ks = 0; ks < 2; ++ks) {
      short8v ap = *(const short8v*)(Ps + (wave * 16 + l15) * 72 + ks * 32 + lg * 8);
#pragma unroll
      for (int j = 0; j < 4; ++j) {
        short8v bv = *(const short8v*)(Vs + (j * 16 + l15) * 72 + ks * 32 + lg * 8);
        oacc[j] = __builtin_amdgcn_mfma_f32_16x16x32_bf16(ap, bv, oacc[j], 0, 0, 0);
      }
    }
  }
#pragma unroll
  for (int r = 0; r < 4; ++r) {
    float inv = lsum[r] > 0.f ? 1.0f / lsum[r] : 0.0f;
    int n = qb * 64 + wave * 16 + lg * 4 + r;
    unsigned short* cp = ctx + ((size_t)b * NQ_ + n) * 512 + h * 64;
#pragma unroll
    for (int j = 0; j < 4; ++j)
      cp[j * 16 + l15] = f2bf(oacc[j][r] * inv);
  }
}

extern "C" void kernel_launch(void* const* d_in, const int* in_sizes, int n_in,
                              void* d_out, int out_size, void* d_ws, size_t ws_size,
                              hipStream_t stream) {
  const float* queries = (const float*)d_in[0];
  const float* keys    = (const float*)d_in[1];
  const float* values  = (const float*)d_in[2];
  const int*   amask   = (const int*)d_in[3];
  const float* Wq = (const float*)d_in[4];
  const float* bq = (const float*)d_in[5];
  const float* Wk = (const float*)d_in[6];
  const float* bk = (const float*)d_in[7];
  const float* Wv = (const float*)d_in[8];
  const float* bv = (const float*)d_in[9];
  const float* Wo = (const float*)d_in[10];
  const float* bo = (const float*)d_in[11];

  float* out_f = (float*)d_out;                           // [8,1024,512]
  float* unnorm = out_f + (size_t)B_ * NQ_ * DM_;         // [8,8,1024,1024]

  char* ws = (char*)d_ws;
  size_t off = 0;
  unsigned short* Xq  = (unsigned short*)(ws + off); off += (size_t)8192 * 512 * 2;
  unsigned short* Xk  = (unsigned short*)(ws + off); off += (size_t)8192 * 512 * 2;
  unsigned short* Xv  = (unsigned short*)(ws + off); off += (size_t)8192 * 512 * 2;
  unsigned short* Wqt = (unsigned short*)(ws + off); off += (size_t)512 * 512 * 2;
  unsigned short* Wkt = (unsigned short*)(ws + off); off += (size_t)512 * 512 * 2;
  unsigned short* Wvt = (unsigned short*)(ws + off); off += (size_t)512 * 512 * 2;
  unsigned short* Wot = (unsigned short*)(ws + off); off += (size_t)512 * 512 * 2;
  unsigned short* qws  = (unsigned short*)(ws + off); off += (size_t)8192 * 512 * 2;
  unsigned short* kws  = (unsigned short*)(ws + off); off += (size_t)8192 * 512 * 2;
  unsigned short* vtws = (unsigned short*)(ws + off); off += (size_t)8192 * 512 * 2;
  unsigned short* ctx  = (unsigned short*)(ws + off); off += (size_t)8192 * 512 * 2;

  conv_bf16<<<2048, 256, 0, stream>>>(queries, Xq, 524288);
  conv_bf16<<<2048, 256, 0, stream>>>(keys,    Xk, 524288);
  conv_bf16<<<2048, 256, 0, stream>>>(values,  Xv, 524288);
  transpose_w<<<1024, 256, 0, stream>>>(Wq, Wqt);
  transpose_w<<<1024, 256, 0, stream>>>(Wk, Wkt);
  transpose_w<<<1024, 256, 0, stream>>>(Wv, Wvt);
  transpose_w<<<1024, 256, 0, stream>>>(Wo, Wot);

  dim3 gg(64, 4);
  gemm_bf16<<<gg, 256, 0, stream>>>(Xq, Wqt, bq, (void*)qws, 0);
  gemm_bf16<<<gg, 256, 0, stream>>>(Xk, Wkt, bk, (void*)kws, 1);
  gemm_bf16<<<gg, 256, 0, stream>>>(Xv, Wvt, bv, (void*)vtws, 2);

  attn_fused<<<1024, 256, 0, stream>>>(qws, kws, vtws, amask, unnorm, ctx);

  gemm_bf16<<<gg, 256, 0, stream>>>(ctx, Wot, bo, d_out, 3);
}